// Round 1
// baseline (146.369 us; speedup 1.0000x reference)
//
#include <hip/hip_runtime.h>
#include <hip/hip_bf16.h>

typedef __attribute__((ext_vector_type(8))) short bf16x8;
typedef __attribute__((ext_vector_type(4))) float f32x4;
typedef unsigned short u16;
typedef unsigned int u32;

#define NP 34                                      // 32 + 2 halo (zero pad)
#define XT_BYTES ((size_t)4 * NP * NP * NP * 128 * 2)   // 40,247,296 B

__device__ __forceinline__ u16 f2bf(float f) {
  __hip_bfloat16 h = __float2bfloat16(f);
  return __builtin_bit_cast(u16, h);
}

__device__ __forceinline__ void gload_lds16(const u16* g, u16* l) {
  __builtin_amdgcn_global_load_lds(
      (const __attribute__((address_space(1))) u32*)g,
      (__attribute__((address_space(3))) u32*)l, 16, 0, 0);
}

// ---------------- kernel 1: demod + modulated bf16 weights ----------------
// wmod[b][tap][oc][ic] = bf16( weight[oc][ic][tap] * y[b][ic] * demod[b][oc] )
__global__ __launch_bounds__(128) void kmodw(const float* __restrict__ w,
                                             const float* __restrict__ y,
                                             u16* __restrict__ wmod) {
  const int oc = blockIdx.x, b = blockIdx.y;
  const int ic = threadIdx.x;               // 128 threads
  const float* wp = w + (oc * 128 + ic) * 27;
  float wv[27];
  float s = 0.f;
#pragma unroll
  for (int t = 0; t < 27; ++t) { wv[t] = wp[t]; s += wv[t] * wv[t]; }
  const float yv = y[b * 128 + ic];
  float v = yv * yv * s;
#pragma unroll
  for (int m = 1; m < 64; m <<= 1) v += __shfl_xor(v, m);
  __shared__ float part[2];
  const int lane = ic & 63, wid = ic >> 6;
  if (lane == 0) part[wid] = v;
  __syncthreads();
  const float demod = rsqrtf(part[0] + part[1] + 1e-8f);
  const float sc = yv * demod;
#pragma unroll
  for (int t = 0; t < 27; ++t)
    wmod[((b * 27 + t) * 128 + oc) * 128 + ic] = f2bf(wv[t] * sc);
}

// ---------------- kernel 2: f32 -> bf16 transpose-cast with zero-pad -------
// x[b][ic][z][y][x] (f32) -> xt[b][z+1][y+1][x+1][ic] (bf16), borders zero.
__global__ __launch_bounds__(256) void kcastx(const float* __restrict__ x,
                                              u16* __restrict__ xt) {
  const int yq = blockIdx.x, z = blockIdx.y, b = blockIdx.z;
  const int tid = threadIdx.x;
  __shared__ u16 t[32 * 132];               // [x][ic], stride 132 kills conflicts
  const float* xp = x + (size_t)b * 128 * 32768 + (z * 32 + yq) * 32;
#pragma unroll
  for (int p = 0; p < 16; ++p) {
    const int ic = p * 8 + (tid >> 5), xx = tid & 31;
    t[xx * 132 + ic] = f2bf(xp[(size_t)ic * 32768 + xx]);
  }
  __syncthreads();
  u16* xtb = xt + (((size_t)(b * NP + z + 1) * NP + (yq + 1)) * NP + 1) * 128;
#pragma unroll
  for (int p = 0; p < 4; ++p) {
    const int xx = p * 8 + (tid >> 5), icq = tid & 31;
    *(ushort4*)(xtb + (size_t)xx * 128 + icq * 4) = *(const ushort4*)&t[xx * 132 + icq * 4];
  }
}

// ---------------- kernel 3: implicit-GEMM conv via MFMA --------------------
// Per block: b, z, 4 y-rows; C[128 oc][128 n] += sum over 27 taps, K=128 ic.
__global__ __launch_bounds__(256, 2) void kconv(const u16* __restrict__ xt,
                                                const u16* __restrict__ wmod,
                                                float* __restrict__ out) {
  __shared__ u16 Alds[16384];   // [oc][ic], XOR-swizzled 16B slots
  __shared__ u16 Blds[16384];   // [n][ic],  XOR-swizzled 16B slots
  const int tid = threadIdx.x;
  const int lane = tid & 63, wid = tid >> 6;
  const int bid = blockIdx.x;
  const int yt = bid & 7;
  const int z = (bid >> 3) & 31;
  const int b = bid >> 8;
  const int y0 = yt << 2;
  const int wm = wid >> 1, wn = wid & 1;    // 2x2 wave grid

  const u16* xb = xt + (size_t)b * (NP * NP * NP) * 128;
  const u16* wb = wmod + (size_t)b * 27 * 16384;

  f32x4 acc[4][4];
#pragma unroll
  for (int i = 0; i < 4; ++i)
#pragma unroll
    for (int j = 0; j < 4; ++j) acc[i][j] = (f32x4){0.f, 0.f, 0.f, 0.f};

  const int sgrp = tid >> 4;                // 0..15: row sub-index per round
  const int slot = tid & 15;                // 16B slot within 256B row

  for (int tap = 0; tap < 27; ++tap) {
    const int dz = tap / 9 - 1;
    const int dy = (tap / 3) % 3 - 1;
    const int dx = tap % 3 - 1;
    __syncthreads();                        // previous tile fully consumed
    // --- stage A (32 KiB): wmod[b][tap][oc][ic], pre-swizzled source ---
    {
      const u16* at = wb + tap * 16384;
#pragma unroll
      for (int r = 0; r < 8; ++r) {
        const int row = (r << 4) + sgrp;    // oc
        const u16* src = at + row * 128 + ((slot ^ (row & 7)) << 3);
        gload_lds16(src, &Alds[r * 2048 + wid * 512]);
      }
    }
    // --- stage B (32 KiB): xt rows for the 128 spatial positions ---
    {
      const int pz = z + 1 + dz;
#pragma unroll
      for (int r = 0; r < 8; ++r) {
        const int n = (r << 4) + sgrp;      // spatial index yy*32+xx
        const int yy = n >> 5, xx = n & 31;
        const int py = y0 + yy + 1 + dy;
        const int px = xx + 1 + dx;
        const u16* src = xb + ((size_t)(pz * NP + py) * NP + px) * 128 +
                         ((slot ^ (n & 7)) << 3);
        gload_lds16(src, &Blds[r * 2048 + wid * 512]);
      }
    }
    __syncthreads();                        // compiler drains vmcnt before barrier
    // --- K-loop: 4 chunks of 32 ic ---
#pragma unroll
    for (int kk = 0; kk < 4; ++kk) {
      bf16x8 af[4], bfr[4];
      const int sg = (kk << 2) + (lane >> 4);   // 16B slot along K
#pragma unroll
      for (int m = 0; m < 4; ++m) {
        const int row = (wm << 6) + (m << 4) + (lane & 15);
        af[m] = *(const bf16x8*)&Alds[row * 128 + ((sg ^ (row & 7)) << 3)];
      }
#pragma unroll
      for (int n = 0; n < 4; ++n) {
        const int row = (wn << 6) + (n << 4) + (lane & 15);
        bfr[n] = *(const bf16x8*)&Blds[row * 128 + ((sg ^ (row & 7)) << 3)];
      }
#pragma unroll
      for (int m = 0; m < 4; ++m)
#pragma unroll
        for (int n = 0; n < 4; ++n)
          acc[m][n] = __builtin_amdgcn_mfma_f32_16x16x32_bf16(af[m], bfr[n],
                                                              acc[m][n], 0, 0, 0);
    }
  }
  // --- epilogue: C/D layout col=lane&15, row=(lane>>4)*4+reg ---
  const int col = lane & 15;
  const int rg = lane >> 4;
#pragma unroll
  for (int m = 0; m < 4; ++m) {
    const int ocb = (wm << 6) + (m << 4) + (rg << 2);
#pragma unroll
    for (int n = 0; n < 4; ++n) {
      const int nn = (wn << 6) + (n << 4) + col;
      const int yy = nn >> 5, xx = nn & 31;
      float* op = out + ((size_t)(b * 128 + ocb) << 15) + (z << 10) +
                  ((y0 + yy) << 5) + xx;
#pragma unroll
      for (int r = 0; r < 4; ++r) op[(size_t)r << 15] = acc[m][n][r];
    }
  }
}

extern "C" void kernel_launch(void* const* d_in, const int* in_sizes, int n_in,
                              void* d_out, int out_size, void* d_ws, size_t ws_size,
                              hipStream_t stream) {
  const float* x = (const float*)d_in[0];
  const float* y = (const float*)d_in[1];
  const float* w = (const float*)d_in[2];
  float* out = (float*)d_out;
  u16* xt = (u16*)d_ws;
  u16* wmod = (u16*)((char*)d_ws + XT_BYTES);

  hipMemsetAsync(d_ws, 0, XT_BYTES, stream);                 // zero halo
  hipLaunchKernelGGL(kmodw, dim3(128, 4), dim3(128), 0, stream, w, y, wmod);
  hipLaunchKernelGGL(kcastx, dim3(32, 32, 4), dim3(256), 0, stream, x, xt);
  hipLaunchKernelGGL(kconv, dim3(1024), dim3(256), 0, stream, xt, wmod, out);
}